// Round 1
// baseline (9415.228 us; speedup 1.0000x reference)
//
#include <hip/hip_runtime.h>
#include <hip/hip_bf16.h>

// 2-layer LSTM (T=512,B=128,IN=544,H=512) + actor/critic heads on MI355X.
// Design:
//  - Persistent kernel, 256 blocks x 256 threads (1 block/CU, 1 wave/SIMD).
//    Blocks 0..127 = layer0, 128..255 = layer1 (dataflow pipeline, no grid barrier).
//  - Per block: batch tile Bt=32 (bg=0..3), hidden tile Ht=16 (jg=0..31).
//    Gate rows (4 gates x 16 j) = 4 MFMA N-tiles; M = batch; K split 4-ways
//    across the block's 4 waves, partials reduced through LDS.
//  - Weights are bf16 B-fragments held IN REGISTERS (~132-144 VGPR/lane),
//    loaded once before the t-loop. No LDS weight traffic in the loop.
//  - Cross-block sync: per-(layer,batch-group) monotonic counters in ws,
//    device(agent)-scope atomics + acquire/release fences (cross-XCD safe).
//    h0 passes through a 16-slot ring (back-pressured); h1 history is kept
//    fully (bf16) and is also the input of the final heads GEMM.
//  - c state lives in registers (fp32). done-mask (0/1) applied to recurrent
//    h fragment loads and to c.
// ws layout: [0,4096) counters | [4096, +2MB) h0 ring | then h1 hist (513 slots).

namespace {
constexpr int T = 512, B = 128, IN = 544, H = 512, NA = 18;
constexpr int BH = B * H;                 // 65536
constexpr int OUT_COLS = NA + 1;          // 19
constexpr int OUT_HT = T * B * OUT_COLS;  // 1245184
constexpr int OUT_CT = OUT_HT + 2 * BH;   // 1376256
}

using f32x4 = __attribute__((ext_vector_type(4))) float;
using s16x8 = __attribute__((ext_vector_type(8))) short;

__device__ __forceinline__ unsigned short f2bu(float f) {
  union { __hip_bfloat16 h; unsigned short u; } cv;
  cv.h = __float2bfloat16(f);
  return cv.u;
}
__device__ __forceinline__ float sigm(float x) { return 1.0f / (1.0f + __expf(-x)); }
__device__ __forceinline__ float tanh_f(float x) { return 1.0f - 2.0f / (1.0f + __expf(2.0f * x)); }

__device__ __forceinline__ void spin_ge(unsigned int* p, unsigned int tgt) {
  while (__hip_atomic_load(p, __ATOMIC_RELAXED, __HIP_MEMORY_SCOPE_AGENT) < tgt)
    __builtin_amdgcn_s_sleep(2);
}

template <int LAYER>
__device__ void lstm_layer(const float* __restrict__ x, const int* __restrict__ done,
                           const float* __restrict__ h0in, const float* __restrict__ c0in,
                           const float* __restrict__ Wih, const float* __restrict__ Whh,
                           const float* __restrict__ bih, const float* __restrict__ bhh,
                           float* __restrict__ out, unsigned short* __restrict__ ring,
                           unsigned short* __restrict__ hist, unsigned int* ctr,
                           int bg, int jg, float* red) {
  constexpr int NKCMAX = (LAYER == 0) ? 9 : 8;  // k-chunks per wave (max)
  const int tid = threadIdx.x;
  const int w = tid >> 6;        // wave 0..3
  const int lane = tid & 63;
  const int lo = lane & 15;
  const int quad = lane >> 4;
  const int bbase = bg * 32, jbase = jg * 16;
  const bool rec = (w >= 2);  // waves 2,3 consume the recurrent (masked) operand

  int kbeg, nkc;
  if (LAYER == 0) { kbeg = (w == 0) ? 0 : (1 + w * 8); nkc = (w == 0) ? 9 : 8; }  // 0..8 | 9..16 | 17..24 | 25..32
  else            { kbeg = w * 8; nkc = 8; }                                       // 0..7 | 8..15 | 16..23 | 24..31

  // ---- load weight B-fragments into registers (once) ----
  // B-frag lane mapping: n(col)=lane&15 -> W row = nt*512 + jbase + lo;
  //                      k = kq*32 + quad*8 + j  (j=0..7 contiguous)
  s16x8 Bf[4][NKCMAX];
#pragma unroll
  for (int kci = 0; kci < NKCMAX; kci++) {
    if (kci < nkc) {
      int kg = (kbeg + kci) * 32 + quad * 8;
#pragma unroll
      for (int nt = 0; nt < 4; nt++) {
        int row = nt * 512 + jbase + lo;
        const float* src;
        if (LAYER == 0) src = (kg < 544) ? (Wih + row * 544 + kg) : (Whh + row * 512 + (kg - 544));
        else            src = (kg < 512) ? (Wih + row * 512 + kg) : (Whh + row * 512 + (kg - 512));
        union { s16x8 v; unsigned short u[8]; } tu;
#pragma unroll
        for (int j = 0; j < 8; j++) tu.u[j] = f2bu(src[j]);
        Bf[nt][kci] = tu.v;
      }
    }
  }

  // bias per gate for this lane's j (col = lo)
  float bias[4];
#pragma unroll
  for (int nt = 0; nt < 4; nt++) {
    int row = nt * 512 + jbase + lo;
    bias[nt] = bih[row] + bhh[row];
  }

  // ---- c state + initial h publication (owner waves 0,1; wave w owns Mtile w) ----
  const int mt = w & 1;
  const int bE0 = bbase + mt * 16 + quad * 4;  // + r
  const int jE = jbase + lo;
  float cst[4] = {0.f, 0.f, 0.f, 0.f};
  if (w < 2) {
#pragma unroll
    for (int r = 0; r < 4; r++) {
      int b = bE0 + r;
      cst[r] = c0in[LAYER * BH + b * 512 + jE];
      unsigned short hu = f2bu(h0in[LAYER * BH + b * 512 + jE]);
      if (LAYER == 0) ring[0 * BH + b * 512 + jE] = hu;  // slot for t=-1
      else            hist[0 * BH + b * 512 + jE] = hu;
    }
  }
  __syncthreads();
  unsigned int* myc = ctr + ((LAYER == 0 ? 0 : 4) + bg) * 16;
  unsigned int* l0c = ctr + (0 + bg) * 16;
  unsigned int* l1c = ctr + (4 + bg) * 16;
  if (tid == 0) {
    __builtin_amdgcn_fence(__ATOMIC_RELEASE, "agent");
    __hip_atomic_fetch_add(myc, 1u, __ATOMIC_RELAXED, __HIP_MEMORY_SCOPE_AGENT);
  }

  // ---- time loop ----
  for (int t = 0; t < T; t++) {
    if (tid == 0) {
      if (LAYER == 0) {
        spin_ge(l0c, 32u * (unsigned)(t + 1));                       // peers done t-1
        if (t >= 16) spin_ge(l1c, 32u * (unsigned)(t - 14));         // ring back-pressure
      } else {
        spin_ge(l0c, 32u * (unsigned)(t + 2));                       // layer0 done t
        spin_ge(l1c, 32u * (unsigned)(t + 1));                       // peers done t-1
      }
      __builtin_amdgcn_fence(__ATOMIC_ACQUIRE, "agent");             // invalidate L1/L2
    }
    __syncthreads();

    // per-Mtile base pointers + recurrent masks
    const unsigned short* prec[2];
    const unsigned short* pin1[2];
    const float* pxf[2];
    bool dA[2];
#pragma unroll
    for (int m2 = 0; m2 < 2; m2++) {
      int b = bbase + m2 * 16 + lo;
      dA[m2] = rec ? (done[t * B + b] != 0) : false;
      if (LAYER == 0) {
        pxf[m2] = x + (size_t)(t * B + b) * 544 + quad * 8;
        prec[m2] = ring + (t & 15) * BH + b * 512 + quad * 8;        // h0[t-1]
      } else {
        pin1[m2] = ring + ((t + 1) & 15) * BH + b * 512 + quad * 8;  // h0[t]
        prec[m2] = hist + (size_t)t * BH + b * 512 + quad * 8;       // h1[t-1]
      }
    }
    const int koff = rec ? (kbeg - (LAYER == 0 ? 17 : 16)) * 32 : kbeg * 32;

    f32x4 acc[2][4];
#pragma unroll
    for (int m2 = 0; m2 < 2; m2++)
#pragma unroll
      for (int nt = 0; nt < 4; nt++) acc[m2][nt] = (f32x4){0.f, 0.f, 0.f, 0.f};

#pragma unroll
    for (int kci = 0; kci < NKCMAX; kci++) {
      if (kci < nkc) {
        int ko = koff + kci * 32;
#pragma unroll
        for (int m2 = 0; m2 < 2; m2++) {
          s16x8 a;
          if (rec) {
            a = *reinterpret_cast<const s16x8*>(prec[m2] + ko);
            if (dA[m2]) a = s16x8{};
          } else if (LAYER == 0) {
            const f32x4* p4 = reinterpret_cast<const f32x4*>(pxf[m2] + ko);
            f32x4 f0 = p4[0], f1 = p4[1];
            union { s16x8 v; unsigned short u[8]; } tu;
#pragma unroll
            for (int j = 0; j < 4; j++) { tu.u[j] = f2bu(f0[j]); tu.u[4 + j] = f2bu(f1[j]); }
            a = tu.v;
          } else {
            a = *reinterpret_cast<const s16x8*>(pin1[m2] + ko);
          }
#pragma unroll
          for (int nt = 0; nt < 4; nt++)
            acc[m2][nt] = __builtin_amdgcn_mfma_f32_16x16x32_bf16(a, Bf[nt][kci], acc[m2][nt], 0, 0, 0);
        }
      }
    }

    // ---- cross-wave K reduction through LDS ----
#pragma unroll
    for (int m2 = 0; m2 < 2; m2++)
#pragma unroll
      for (int nt = 0; nt < 4; nt++)
#pragma unroll
        for (int r = 0; r < 4; r++)
          red[(((w * 2 + m2) * 16) + nt * 4 + r) * 64 + lane] = acc[m2][nt][r];
    __syncthreads();

    if (w < 2) {
      float g[4][4];
#pragma unroll
      for (int nt = 0; nt < 4; nt++)
#pragma unroll
        for (int r = 0; r < 4; r++) {
          int f = nt * 4 + r;
          g[nt][r] = red[((0 * 2 + mt) * 16 + f) * 64 + lane] + red[((1 * 2 + mt) * 16 + f) * 64 + lane] +
                     red[((2 * 2 + mt) * 16 + f) * 64 + lane] + red[((3 * 2 + mt) * 16 + f) * 64 + lane];
        }
#pragma unroll
      for (int r = 0; r < 4; r++) {
        int b = bE0 + r;
        float iv = g[0][r] + bias[0];
        float fv = g[1][r] + bias[1];
        float gv = g[2][r] + bias[2];
        float ov = g[3][r] + bias[3];
        float cp = (done[t * B + b] != 0) ? 0.0f : cst[r];
        float cn = sigm(fv) * cp + sigm(iv) * tanh_f(gv);
        float hn = sigm(ov) * tanh_f(cn);
        cst[r] = cn;
        unsigned short hu = f2bu(hn);
        if (LAYER == 0) ring[((t + 1) & 15) * BH + b * 512 + jE] = hu;
        else            hist[(size_t)(t + 1) * BH + b * 512 + jE] = hu;
        if (t == T - 1) {
          out[OUT_HT + LAYER * BH + b * 512 + jE] = hn;
          out[OUT_CT + LAYER * BH + b * 512 + jE] = cn;
        }
      }
    }
    __syncthreads();
    if (tid == 0) {
      __builtin_amdgcn_fence(__ATOMIC_RELEASE, "agent");
      __hip_atomic_fetch_add(myc, 1u, __ATOMIC_RELAXED, __HIP_MEMORY_SCOPE_AGENT);
    }
  }
}

__global__ __launch_bounds__(256, 1) void lstm_persist(
    const float* x, const int* done, const float* h0in, const float* c0in,
    const float* Wih0, const float* Whh0, const float* bih0, const float* bhh0,
    const float* Wih1, const float* Whh1, const float* bih1, const float* bhh1,
    float* out, unsigned short* ring, unsigned short* hist, unsigned int* ctr) {
  __shared__ float red[8192];
  const int bid = blockIdx.x;
  const int layer = bid >> 7;
  const int bl = bid & 127;
  const int bg = bl >> 5, jg = bl & 31;
  if (layer == 0)
    lstm_layer<0>(x, done, h0in, c0in, Wih0, Whh0, bih0, bhh0, out, ring, hist, ctr, bg, jg, red);
  else
    lstm_layer<1>(x, done, h0in, c0in, Wih1, Whh1, bih1, bhh1, out, ring, hist, ctr, bg, jg, red);
}

// heads: out[m, 0..18] = hidden[m,:] @ [W_actor; W_critic]^T + bias, m = t*B+b
__global__ __launch_bounds__(256) void head_kernel(const unsigned short* __restrict__ hidden,
                                                   const float* __restrict__ Wa, const float* __restrict__ ba,
                                                   const float* __restrict__ Wc, const float* __restrict__ bc,
                                                   float* __restrict__ out) {
  const int tid = threadIdx.x, w = tid >> 6, lane = tid & 63, lo = lane & 15, quad = lane >> 4;
  const int mbase = blockIdx.x * 128;
  s16x8 Bf[2][16];
#pragma unroll
  for (int nt = 0; nt < 2; nt++) {
    int row = nt * 16 + lo;
#pragma unroll
    for (int kc = 0; kc < 16; kc++) {
      int kg = kc * 32 + quad * 8;
      union { s16x8 v; unsigned short u[8]; } tu;
      if (row < 18) {
        const float* s = Wa + row * 512 + kg;
#pragma unroll
        for (int j = 0; j < 8; j++) tu.u[j] = f2bu(s[j]);
      } else if (row == 18) {
        const float* s = Wc + kg;
#pragma unroll
        for (int j = 0; j < 8; j++) tu.u[j] = f2bu(s[j]);
      } else {
        tu.v = s16x8{};
      }
      Bf[nt][kc] = tu.v;
    }
  }
  f32x4 acc[2][2];
#pragma unroll
  for (int mi = 0; mi < 2; mi++)
#pragma unroll
    for (int nt = 0; nt < 2; nt++) acc[mi][nt] = (f32x4){0.f, 0.f, 0.f, 0.f};
#pragma unroll
  for (int kc = 0; kc < 16; kc++) {
#pragma unroll
    for (int mi = 0; mi < 2; mi++) {
      int m = mbase + (w * 2 + mi) * 16 + lo;
      s16x8 a = *reinterpret_cast<const s16x8*>(hidden + (size_t)m * 512 + kc * 32 + quad * 8);
      acc[mi][0] = __builtin_amdgcn_mfma_f32_16x16x32_bf16(a, Bf[0][kc], acc[mi][0], 0, 0, 0);
      acc[mi][1] = __builtin_amdgcn_mfma_f32_16x16x32_bf16(a, Bf[1][kc], acc[mi][1], 0, 0, 0);
    }
  }
  float b0 = ba[lo];                                               // cols 0..15
  float b1 = (lo < 2) ? ba[16 + lo] : ((lo == 2) ? bc[0] : 0.f);   // cols 16,17,18
#pragma unroll
  for (int mi = 0; mi < 2; mi++)
#pragma unroll
    for (int r = 0; r < 4; r++) {
      int m = mbase + (w * 2 + mi) * 16 + quad * 4 + r;
      out[(size_t)m * 19 + lo] = acc[mi][0][r] + b0;
      if (lo < 3) out[(size_t)m * 19 + 16 + lo] = acc[mi][1][r] + b1;
    }
}

extern "C" void kernel_launch(void* const* d_in, const int* in_sizes, int n_in,
                              void* d_out, int out_size, void* d_ws, size_t ws_size,
                              hipStream_t stream) {
  const float* x = (const float*)d_in[0];
  const int* done = (const int*)d_in[1];
  const float* h0 = (const float*)d_in[2];
  const float* c0 = (const float*)d_in[3];
  const float* Wih0 = (const float*)d_in[4];
  const float* Whh0 = (const float*)d_in[5];
  const float* bih0 = (const float*)d_in[6];
  const float* bhh0 = (const float*)d_in[7];
  const float* Wih1 = (const float*)d_in[8];
  const float* Whh1 = (const float*)d_in[9];
  const float* bih1 = (const float*)d_in[10];
  const float* bhh1 = (const float*)d_in[11];
  const float* Wa = (const float*)d_in[12];
  const float* ba = (const float*)d_in[13];
  const float* Wc = (const float*)d_in[14];
  const float* bc = (const float*)d_in[15];
  float* out = (float*)d_out;

  char* ws = (char*)d_ws;
  unsigned int* ctr = (unsigned int*)ws;                               // 4 KB
  unsigned short* ring = (unsigned short*)(ws + 4096);                 // 16*65536*2 = 2 MB
  unsigned short* hist = (unsigned short*)(ws + 4096 + 16 * 65536 * 2);// 513*65536*2 ≈ 64 MB
  // total ws needed ≈ 66.2 MB

  hipMemsetAsync(ctr, 0, 4096, stream);
  lstm_persist<<<dim3(256), dim3(256), 0, stream>>>(
      x, done, h0, c0, Wih0, Whh0, bih0, bhh0, Wih1, Whh1, bih1, bhh1,
      out, ring, hist, ctr);
  head_kernel<<<dim3(512), dim3(256), 0, stream>>>(hist + 65536, Wa, ba, Wc, bc, out);
}

// Round 2
// 6636.033 us; speedup vs baseline: 1.4188x; 1.4188x over previous
//
#include <hip/hip_runtime.h>
#include <hip/hip_bf16.h>

// 2-layer LSTM (T=512,B=128,IN=544,H=512) + actor/critic heads on MI355X.
// R2: replace agent fences (buffer_inv/wbl2 = whole-L2 flush per step, the R1
// bottleneck) with per-access coherence: all cross-block data moves via
// relaxed agent-scope 8B atomic load/store (sc1 -> served at Infinity Cache,
// bypassing the non-coherent per-XCD L2s). Sync via per-block flag array
// (one relaxed atomic store per producer; consumers spin 64-lane + __all).
//
//  - Persistent kernel, 256 blocks x 256 threads (1 block/CU).
//    Blocks 0..127 = layer0, 128..255 = layer1 (dataflow pipeline).
//  - Per block: batch tile 32 (bg), hidden tile 16 (jg). Weights bf16 held
//    in registers (~144 VGPR). K split across 4 waves; LDS reduction.
//  - Waves 0,1 consume the non-recurrent operand (x / h0[t]); waves 2,3 the
//    recurrent one. Each wave spins only on its own dependency.
// ws: [0,4KB) flags | [4KB,+2MB) h0 ring (16 slots) | h1 hist (513 slots).

namespace {
constexpr int T = 512, B = 128, H = 512, NA = 18;
constexpr int BH = B * H;                 // 65536
constexpr int OUT_COLS = NA + 1;          // 19
constexpr int OUT_HT = T * B * OUT_COLS;  // 1245184
constexpr int OUT_CT = OUT_HT + 2 * BH;   // 1376256
}

using f32x4 = __attribute__((ext_vector_type(4))) float;
using s16x8 = __attribute__((ext_vector_type(8))) short;

__device__ __forceinline__ unsigned short f2bu(float f) {
  union { __hip_bfloat16 h; unsigned short u; } cv;
  cv.h = __float2bfloat16(f);
  return cv.u;
}
__device__ __forceinline__ float sigm(float x) { return 1.0f / (1.0f + __expf(-x)); }
__device__ __forceinline__ float tanh_f(float x) { return 1.0f - 2.0f / (1.0f + __expf(2.0f * x)); }

// All 64 lanes poll 32 per-block flags (lane&31); exit when all >= tgt.
__device__ __forceinline__ void spin_group(const unsigned int* f, unsigned int tgt) {
  const unsigned int* p = f + (threadIdx.x & 31);
  for (;;) {
    unsigned int v = __hip_atomic_load(p, __ATOMIC_RELAXED, __HIP_MEMORY_SCOPE_AGENT);
    if (__all((int)(v >= tgt))) break;
    __builtin_amdgcn_s_sleep(1);
  }
}

// 16B fragment load through the coherence point (two 8B relaxed agent loads).
__device__ __forceinline__ s16x8 ld_frag_agent(const unsigned short* p) {
  const unsigned long long* q = (const unsigned long long*)p;
  unsigned long long a0 = __hip_atomic_load(q, __ATOMIC_RELAXED, __HIP_MEMORY_SCOPE_AGENT);
  unsigned long long a1 = __hip_atomic_load(q + 1, __ATOMIC_RELAXED, __HIP_MEMORY_SCOPE_AGENT);
  union { unsigned long long u[2]; s16x8 v; } r;
  r.u[0] = a0; r.u[1] = a1;
  return r.v;
}

template <int LAYER>
__device__ void lstm_layer(const float* __restrict__ x, const int* __restrict__ done,
                           const float* __restrict__ h0in, const float* __restrict__ c0in,
                           const float* __restrict__ Wih, const float* __restrict__ Whh,
                           const float* __restrict__ bih, const float* __restrict__ bhh,
                           float* __restrict__ out, unsigned short* __restrict__ ring,
                           unsigned short* __restrict__ hist, unsigned int* flags,
                           int bg, int jg, float* red, unsigned short (*hrep)[16][20]) {
  constexpr int NKCMAX = (LAYER == 0) ? 9 : 8;
  const int tid = threadIdx.x;
  const int w = tid >> 6;
  const int lane = tid & 63;
  const int lo = lane & 15;
  const int quad = lane >> 4;
  const int bbase = bg * 32, jbase = jg * 16;
  const bool rec = (w >= 2);  // waves 2,3: recurrent operand

  int kbeg, nkc;
  if (LAYER == 0) { kbeg = (w == 0) ? 0 : (1 + w * 8); nkc = (w == 0) ? 9 : 8; }  // x: chunks 0..16, h: 17..32
  else            { kbeg = w * 8; nkc = 8; }                                       // in1: 0..15, h: 16..31

  // ---- weight B-fragments in registers ----
  s16x8 Bf[4][NKCMAX];
#pragma unroll
  for (int kci = 0; kci < NKCMAX; kci++) {
    if (kci < nkc) {
      int kg = (kbeg + kci) * 32 + quad * 8;
#pragma unroll
      for (int nt = 0; nt < 4; nt++) {
        int row = nt * 512 + jbase + lo;
        const float* src;
        if (LAYER == 0) src = (kg < 544) ? (Wih + row * 544 + kg) : (Whh + row * 512 + (kg - 544));
        else            src = (kg < 512) ? (Wih + row * 512 + kg) : (Whh + row * 512 + (kg - 512));
        union { s16x8 v; unsigned short u[8]; } tu;
#pragma unroll
        for (int j = 0; j < 8; j++) tu.u[j] = f2bu(src[j]);
        Bf[nt][kci] = tu.v;
      }
    }
  }

  float bias[4];
#pragma unroll
  for (int nt = 0; nt < 4; nt++) {
    int row = nt * 512 + jbase + lo;
    bias[nt] = bih[row] + bhh[row];
  }

  const int mt = w & 1;                        // epilogue M-tile for waves 0,1
  const int bE0 = bbase + mt * 16 + quad * 4;  // + r
  const int jE = jbase + lo;
  float cst[4] = {0.f, 0.f, 0.f, 0.f};

  unsigned short* slot0 = (LAYER == 0) ? ring : hist;
  if (w < 2) {
#pragma unroll
    for (int r = 0; r < 4; r++) cst[r] = c0in[LAYER * BH + (bE0 + r) * 512 + jE];
    // initial h publication: lane -> 8B chunk (b = lane>>2, j0 = (lane&3)*4)
    int bI = bbase + mt * 16 + (lane >> 2);
    int jI = jbase + (lane & 3) * 4;
    const float* hp = h0in + LAYER * BH + bI * 512 + jI;
    union { unsigned long long u; unsigned short s[4]; } pk;
#pragma unroll
    for (int j = 0; j < 4; j++) pk.s[j] = f2bu(hp[j]);
    __hip_atomic_store((unsigned long long*)(slot0 + bI * 512 + jI), pk.u,
                       __ATOMIC_RELAXED, __HIP_MEMORY_SCOPE_AGENT);
  }
  __syncthreads();  // drains each wave's stores before flag publish

  const unsigned int* fl0 = flags + (0 + bg) * 32;
  const unsigned int* fl1 = flags + (4 + bg) * 32;
  unsigned int* myflag = (unsigned int*)((LAYER == 0 ? fl0 : fl1) + jg);
  if (tid == 0) {
    __builtin_amdgcn_s_waitcnt(0);
    __hip_atomic_store(myflag, 1u, __ATOMIC_RELAXED, __HIP_MEMORY_SCOPE_AGENT);
  }

  for (int t = 0; t < T; t++) {
    // per-wave dependency spin (flag value = completed steps + 1)
    if (LAYER == 0) {
      if (rec) spin_group(fl0, (unsigned)(t + 1));                // peers' h0[t-1]
      else if (t >= 16) spin_group(fl1, (unsigned)(t - 14));      // ring slot free
    } else {
      if (rec) spin_group(fl1, (unsigned)(t + 1));                // peers' h1[t-1]
      else     spin_group(fl0, (unsigned)(t + 2));                // layer0's h0[t]
    }

    const unsigned short* prec[2];
    const unsigned short* pin1[2];
    const float* pxf[2];
    bool dA[2];
#pragma unroll
    for (int m2 = 0; m2 < 2; m2++) {
      int b = bbase + m2 * 16 + lo;
      dA[m2] = rec ? (done[t * B + b] != 0) : false;
      if (LAYER == 0) {
        pxf[m2] = x + (size_t)(t * B + b) * 544 + quad * 8;
        prec[m2] = ring + (t & 15) * BH + b * 512 + quad * 8;         // h0[t-1]
      } else {
        pin1[m2] = ring + ((t + 1) & 15) * BH + b * 512 + quad * 8;   // h0[t]
        prec[m2] = hist + (size_t)t * BH + b * 512 + quad * 8;        // h1[t-1]
      }
    }
    const int koff = rec ? (kbeg - (LAYER == 0 ? 17 : 16)) * 32 : kbeg * 32;

    f32x4 acc[2][4];
#pragma unroll
    for (int m2 = 0; m2 < 2; m2++)
#pragma unroll
      for (int nt = 0; nt < 4; nt++) acc[m2][nt] = (f32x4){0.f, 0.f, 0.f, 0.f};

#pragma unroll
    for (int kci = 0; kci < NKCMAX; kci++) {
      if (kci < nkc) {
        int ko = koff + kci * 32;
#pragma unroll
        for (int m2 = 0; m2 < 2; m2++) {
          s16x8 a;
          if (rec) {
            a = ld_frag_agent(prec[m2] + ko);
            if (dA[m2]) a = s16x8{};
          } else if (LAYER == 0) {
            const f32x4* p4 = reinterpret_cast<const f32x4*>(pxf[m2] + ko);
            f32x4 f0 = p4[0], f1 = p4[1];
            union { s16x8 v; unsigned short u[8]; } tu;
#pragma unroll
            for (int j = 0; j < 4; j++) { tu.u[j] = f2bu(f0[j]); tu.u[4 + j] = f2bu(f1[j]); }
            a = tu.v;
          } else {
            a = ld_frag_agent(pin1[m2] + ko);
          }
#pragma unroll
          for (int nt = 0; nt < 4; nt++)
            acc[m2][nt] = __builtin_amdgcn_mfma_f32_16x16x32_bf16(a, Bf[nt][kci], acc[m2][nt], 0, 0, 0);
        }
      }
    }

    // cross-wave K reduction through LDS
#pragma unroll
    for (int m2 = 0; m2 < 2; m2++)
#pragma unroll
      for (int nt = 0; nt < 4; nt++)
#pragma unroll
        for (int r = 0; r < 4; r++)
          red[(((w * 2 + m2) * 16) + nt * 4 + r) * 64 + lane] = acc[m2][nt][r];
    __syncthreads();  // barrier A

    if (w < 2) {
      float g[4][4];
#pragma unroll
      for (int nt = 0; nt < 4; nt++)
#pragma unroll
        for (int r = 0; r < 4; r++) {
          int f = nt * 4 + r;
          g[nt][r] = red[((0 * 2 + mt) * 16 + f) * 64 + lane] + red[((1 * 2 + mt) * 16 + f) * 64 + lane] +
                     red[((2 * 2 + mt) * 16 + f) * 64 + lane] + red[((3 * 2 + mt) * 16 + f) * 64 + lane];
        }
      float hnv[4], cnv[4];
#pragma unroll
      for (int r = 0; r < 4; r++) {
        int b = bE0 + r;
        float iv = g[0][r] + bias[0];
        float fv = g[1][r] + bias[1];
        float gv = g[2][r] + bias[2];
        float ov = g[3][r] + bias[3];
        float cp = (done[t * B + b] != 0) ? 0.0f : cst[r];
        float cn = sigm(fv) * cp + sigm(iv) * tanh_f(gv);
        float hn = sigm(ov) * tanh_f(cn);
        cst[r] = cn; hnv[r] = hn; cnv[r] = cn;
        hrep[mt][quad * 4 + r][lo] = f2bu(hn);  // transpose tile (same-wave)
      }
      // repack: lane -> 8B chunk (b2 = lane>>2, j0 = (lane&3)*4)
      int b2 = lane >> 2, j0l = (lane & 3) * 4;
      unsigned long long pv = *(const unsigned long long*)&hrep[mt][b2][j0l];
      int bS = bbase + mt * 16 + b2, jS = jbase + j0l;
      unsigned short* dstbase = (LAYER == 0) ? (ring + ((t + 1) & 15) * BH)
                                             : (hist + (size_t)(t + 1) * BH);
      __hip_atomic_store((unsigned long long*)(dstbase + bS * 512 + jS), pv,
                         __ATOMIC_RELAXED, __HIP_MEMORY_SCOPE_AGENT);
      if (t == T - 1) {
#pragma unroll
        for (int r = 0; r < 4; r++) {
          int b = bE0 + r;
          out[OUT_HT + LAYER * BH + b * 512 + jE] = hnv[r];
          out[OUT_CT + LAYER * BH + b * 512 + jE] = cnv[r];
        }
      }
    }
    __syncthreads();  // barrier B (drains epilogue stores; protects red WAR)
    if (tid == 0) {
      __builtin_amdgcn_s_waitcnt(0);
      __hip_atomic_store(myflag, (unsigned)(t + 2), __ATOMIC_RELAXED, __HIP_MEMORY_SCOPE_AGENT);
    }
  }
}

__global__ __launch_bounds__(256, 1) void lstm_persist(
    const float* x, const int* done, const float* h0in, const float* c0in,
    const float* Wih0, const float* Whh0, const float* bih0, const float* bhh0,
    const float* Wih1, const float* Whh1, const float* bih1, const float* bhh1,
    float* out, unsigned short* ring, unsigned short* hist, unsigned int* flags) {
  __shared__ float red[8192];
  __shared__ unsigned short hrep[2][16][20];
  const int bid = blockIdx.x;
  const int layer = bid >> 7;
  const int bl = bid & 127;
  const int bg = bl >> 5, jg = bl & 31;
  if (layer == 0)
    lstm_layer<0>(x, done, h0in, c0in, Wih0, Whh0, bih0, bhh0, out, ring, hist, flags, bg, jg, red, hrep);
  else
    lstm_layer<1>(x, done, h0in, c0in, Wih1, Whh1, bih1, bhh1, out, ring, hist, flags, bg, jg, red, hrep);
}

// heads: out[m, 0..18] = hidden[m,:] @ [W_actor; W_critic]^T + bias
__global__ __launch_bounds__(256) void head_kernel(const unsigned short* __restrict__ hidden,
                                                   const float* __restrict__ Wa, const float* __restrict__ ba,
                                                   const float* __restrict__ Wc, const float* __restrict__ bc,
                                                   float* __restrict__ out) {
  const int tid = threadIdx.x, w = tid >> 6, lane = tid & 63, lo = lane & 15, quad = lane >> 4;
  const int mbase = blockIdx.x * 128;
  s16x8 Bf[2][16];
#pragma unroll
  for (int nt = 0; nt < 2; nt++) {
    int row = nt * 16 + lo;
#pragma unroll
    for (int kc = 0; kc < 16; kc++) {
      int kg = kc * 32 + quad * 8;
      union { s16x8 v; unsigned short u[8]; } tu;
      if (row < 18) {
        const float* s = Wa + row * 512 + kg;
#pragma unroll
        for (int j = 0; j < 8; j++) tu.u[j] = f2bu(s[j]);
      } else if (row == 18) {
        const float* s = Wc + kg;
#pragma unroll
        for (int j = 0; j < 8; j++) tu.u[j] = f2bu(s[j]);
      } else {
        tu.v = s16x8{};
      }
      Bf[nt][kc] = tu.v;
    }
  }
  f32x4 acc[2][2];
#pragma unroll
  for (int mi = 0; mi < 2; mi++)
#pragma unroll
    for (int nt = 0; nt < 2; nt++) acc[mi][nt] = (f32x4){0.f, 0.f, 0.f, 0.f};
#pragma unroll
  for (int kc = 0; kc < 16; kc++) {
#pragma unroll
    for (int mi = 0; mi < 2; mi++) {
      int m = mbase + (w * 2 + mi) * 16 + lo;
      s16x8 a = *reinterpret_cast<const s16x8*>(hidden + (size_t)m * 512 + kc * 32 + quad * 8);
      acc[mi][0] = __builtin_amdgcn_mfma_f32_16x16x32_bf16(a, Bf[0][kc], acc[mi][0], 0, 0, 0);
      acc[mi][1] = __builtin_amdgcn_mfma_f32_16x16x32_bf16(a, Bf[1][kc], acc[mi][1], 0, 0, 0);
    }
  }
  float b0 = ba[lo];
  float b1 = (lo < 2) ? ba[16 + lo] : ((lo == 2) ? bc[0] : 0.f);
#pragma unroll
  for (int mi = 0; mi < 2; mi++)
#pragma unroll
    for (int r = 0; r < 4; r++) {
      int m = mbase + (w * 2 + mi) * 16 + quad * 4 + r;
      out[(size_t)m * 19 + lo] = acc[mi][0][r] + b0;
      if (lo < 3) out[(size_t)m * 19 + 16 + lo] = acc[mi][1][r] + b1;
    }
}

extern "C" void kernel_launch(void* const* d_in, const int* in_sizes, int n_in,
                              void* d_out, int out_size, void* d_ws, size_t ws_size,
                              hipStream_t stream) {
  const float* x = (const float*)d_in[0];
  const int* done = (const int*)d_in[1];
  const float* h0 = (const float*)d_in[2];
  const float* c0 = (const float*)d_in[3];
  const float* Wih0 = (const float*)d_in[4];
  const float* Whh0 = (const float*)d_in[5];
  const float* bih0 = (const float*)d_in[6];
  const float* bhh0 = (const float*)d_in[7];
  const float* Wih1 = (const float*)d_in[8];
  const float* Whh1 = (const float*)d_in[9];
  const float* bih1 = (const float*)d_in[10];
  const float* bhh1 = (const float*)d_in[11];
  const float* Wa = (const float*)d_in[12];
  const float* ba = (const float*)d_in[13];
  const float* Wc = (const float*)d_in[14];
  const float* bc = (const float*)d_in[15];
  float* out = (float*)d_out;

  char* ws = (char*)d_ws;
  unsigned int* flags = (unsigned int*)ws;                              // 1 KB used
  unsigned short* ring = (unsigned short*)(ws + 4096);                  // 2 MB
  unsigned short* hist = (unsigned short*)(ws + 4096 + 16 * 65536 * 2); // ~64 MB

  hipMemsetAsync(flags, 0, 4096, stream);
  lstm_persist<<<dim3(256), dim3(256), 0, stream>>>(
      x, done, h0, c0, Wih0, Whh0, bih0, bhh0, Wih1, Whh1, bih1, bhh1,
      out, ring, hist, flags);
  head_kernel<<<dim3(512), dim3(256), 0, stream>>>(hist + 65536, Wa, ba, Wc, bc, out);
}